// Round 7
// baseline (252.232 us; speedup 1.0000x reference)
//
#include <hip/hip_runtime.h>

// HingeLoss: B=4M rows, 7 classes.
// elem = mask ? |logit - target| : relu(logit - target); out = sum(elem)
// mask[i][j] = (j in repr_num[i][0..2]);  target = (label==1) ? 1 : 0
//
// R7: nontemporal loads (R6's win) + 8 rows per thread = 22 independent
// dwordx4 loads in flight per thread before first use (2x R6's 11).
// Probes whether per-wave outstanding-load depth is the binding term of
// the read-latency x concurrency product. Exact cover at B=4M:
// 2048 blocks x 256 threads x 2 chunks = 1,048,576 chunks.

#define NCLS 7

typedef float f32x4 __attribute__((ext_vector_type(4)));
typedef int   i32x4 __attribute__((ext_vector_type(4)));

__device__ __forceinline__ f32x4 ntf(const f32x4* p) { return __builtin_nontemporal_load(p); }
__device__ __forceinline__ i32x4 nti(const i32x4* p) { return __builtin_nontemporal_load(p); }

// one 4-row chunk from pre-loaded registers
__device__ __forceinline__ float chunk_sum(const f32x4 L[7], i32x4 lab,
                                           const i32x4 R[3]) {
    int rv[12];
    #pragma unroll
    for (int c = 0; c < 3; ++c) {
        rv[4*c+0] = R[c][0]; rv[4*c+1] = R[c][1];
        rv[4*c+2] = R[c][2]; rv[4*c+3] = R[c][3];
    }
    float f[28];
    #pragma unroll
    for (int c = 0; c < 7; ++c) {
        f[4*c+0] = L[c][0]; f[4*c+1] = L[c][1];
        f[4*c+2] = L[c][2]; f[4*c+3] = L[c][3];
    }
    float acc = 0.0f;
    #pragma unroll
    for (int k = 0; k < 4; ++k) {
        unsigned m = (1u << rv[3*k]) | (1u << rv[3*k+1]) | (1u << rv[3*k+2]);
        float tgt = (lab[k] == 1) ? 1.0f : 0.0f;
        #pragma unroll
        for (int j = 0; j < NCLS; ++j) {
            float d = f[7*k + j] - tgt;
            acc += ((m >> j) & 1u) ? fabsf(d) : fmaxf(d, 0.0f);
        }
    }
    return acc;
}

__global__ __launch_bounds__(256) void hinge_partial_kernel(
    const f32x4* __restrict__ logit4,    // [7*nchunk]
    const i32x4* __restrict__ label4,    // [nchunk]
    const i32x4* __restrict__ repr4,     // [3*nchunk]
    float* __restrict__ partials,        // [gridDim.x]
    int nchunk)                          // B/4
{
    const int tid = blockIdx.x * blockDim.x + threadIdx.x;
    const int t0  = 2 * tid;

    float acc = 0.0f;
    if (t0 + 1 < nchunk) {
        // issue all 22 independent nt loads up front (compiler schedules
        // them back-to-back; all results are statically indexed -> VGPRs)
        f32x4 L[14];
        #pragma unroll
        for (int c = 0; c < 14; ++c) L[c] = ntf(logit4 + 7 * (size_t)t0 + c);
        i32x4 lab0 = nti(label4 + t0);
        i32x4 lab1 = nti(label4 + t0 + 1);
        i32x4 R[6];
        #pragma unroll
        for (int c = 0; c < 6; ++c) R[c] = nti(repr4 + 3 * (size_t)t0 + c);

        acc += chunk_sum(&L[0], lab0, &R[0]);
        acc += chunk_sum(&L[7], lab1, &R[3]);
    } else if (t0 < nchunk) {
        f32x4 L[7];
        #pragma unroll
        for (int c = 0; c < 7; ++c) L[c] = ntf(logit4 + 7 * (size_t)t0 + c);
        i32x4 lab = nti(label4 + t0);
        i32x4 R[3];
        #pragma unroll
        for (int c = 0; c < 3; ++c) R[c] = nti(repr4 + 3 * (size_t)t0 + c);
        acc += chunk_sum(L, lab, R);
    }

    // wave (64-lane) butterfly reduce
    #pragma unroll
    for (int off = 32; off > 0; off >>= 1)
        acc += __shfl_down(acc, off, 64);

    __shared__ float wave_sums[4];
    if ((threadIdx.x & 63) == 0) wave_sums[threadIdx.x >> 6] = acc;
    __syncthreads();
    if (threadIdx.x == 0)
        partials[blockIdx.x] = wave_sums[0] + wave_sums[1] + wave_sums[2] + wave_sums[3];
}

__global__ __launch_bounds__(256) void reduce_partials_kernel(
    const float* __restrict__ partials, int nblk,
    const float* __restrict__ logit, const int* __restrict__ label,
    const int* __restrict__ repr, int tail_start, int B,
    float* __restrict__ out)
{
    float a = 0.0f;
    for (int i = threadIdx.x; i < nblk; i += 256)
        a += partials[i];

    // rows beyond 4*nchunk (B % 4; zero for B=4M)
    for (int i = tail_start + threadIdx.x; i < B; i += 256) {
        float tgt = (label[i] == 1) ? 1.0f : 0.0f;
        unsigned m = (1u << repr[3*i]) | (1u << repr[3*i+1]) | (1u << repr[3*i+2]);
        #pragma unroll
        for (int j = 0; j < NCLS; ++j) {
            float d = logit[i * NCLS + j] - tgt;
            a += ((m >> j) & 1u) ? fabsf(d) : fmaxf(d, 0.0f);
        }
    }

    #pragma unroll
    for (int off = 32; off > 0; off >>= 1)
        a += __shfl_down(a, off, 64);

    __shared__ float wave_sums[4];
    if ((threadIdx.x & 63) == 0) wave_sums[threadIdx.x >> 6] = a;
    __syncthreads();
    if (threadIdx.x == 0)
        out[0] = wave_sums[0] + wave_sums[1] + wave_sums[2] + wave_sums[3];
}

extern "C" void kernel_launch(void* const* d_in, const int* in_sizes, int n_in,
                              void* d_out, int out_size, void* d_ws, size_t ws_size,
                              hipStream_t stream) {
    const f32x4* logit4 = (const f32x4*)d_in[0];
    const i32x4* label4 = (const i32x4*)d_in[1];
    const i32x4* repr4  = (const i32x4*)d_in[2];
    float*       out    = (float*)d_out;
    float*       partials = (float*)d_ws;

    int B = in_sizes[1];       // label is [B]
    int nchunk = B / 4;        // 1,000,000
    int tail_start = nchunk * 4;

    int threads = 256;
    int pairs = (nchunk + 1) / 2;
    int blocks = (pairs + threads - 1) / threads;   // 2048 for B=4M

    hinge_partial_kernel<<<blocks, threads, 0, stream>>>(logit4, label4, repr4, partials, nchunk);
    reduce_partials_kernel<<<1, 256, 0, stream>>>(
        partials, blocks, (const float*)d_in[0], (const int*)d_in[1],
        (const int*)d_in[2], tail_start, B, out);
}

// Round 8
// 220.434 us; speedup vs baseline: 1.1443x; 1.1443x over previous
//
#include <hip/hip_runtime.h>

// HingeLoss: B=4M rows, 7 classes.
// elem = mask ? |logit - target| : relu(logit - target); out = sum(elem)
// mask[i][j] = (j in repr_num[i][0..2]);  target = (label==1) ? 1 : 0
//
// R8 = revert to R6 (best known). Register-direct float4 nontemporal loads,
// grid-stride (112 B lane stride preserves L3 hits + line merging),
// per-block partials in d_ws, no atomics, separate tiny reduce kernel.
// Seven structural variants (scalar, vec, LDS-staged, DMA-staged, no-atomic,
// deep-ILP, nt) converge at ~2.6-3 TB/s: latency-bound pure-read service
// cap (~64 outstanding 64B sectors/CU x ~450ns). nt loads (skip dirty-L3
// victim allocation) are the only measured improvement.

#define NCLS 7
#define NBLK 2048

typedef float f32x4 __attribute__((ext_vector_type(4)));
typedef int   i32x4 __attribute__((ext_vector_type(4)));

__device__ __forceinline__ f32x4 ntload_f4(const f32x4* p) {
    return __builtin_nontemporal_load(p);
}
__device__ __forceinline__ i32x4 ntload_i4(const i32x4* p) {
    return __builtin_nontemporal_load(p);
}

__global__ __launch_bounds__(256) void hinge_partial_kernel(
    const f32x4* __restrict__ logit4,    // [7*nchunk]
    const i32x4* __restrict__ label4,    // [nchunk]
    const i32x4* __restrict__ repr4,     // [3*nchunk]
    float* __restrict__ partials,        // [gridDim.x]
    int nchunk)                          // B/4
{
    int tid = blockIdx.x * blockDim.x + threadIdx.x;
    int stride = gridDim.x * blockDim.x;

    float acc = 0.0f;
    for (int t = tid; t < nchunk; t += stride) {
        f32x4 L0 = ntload_f4(logit4 + 7 * (size_t)t + 0);
        f32x4 L1 = ntload_f4(logit4 + 7 * (size_t)t + 1);
        f32x4 L2 = ntload_f4(logit4 + 7 * (size_t)t + 2);
        f32x4 L3 = ntload_f4(logit4 + 7 * (size_t)t + 3);
        f32x4 L4 = ntload_f4(logit4 + 7 * (size_t)t + 4);
        f32x4 L5 = ntload_f4(logit4 + 7 * (size_t)t + 5);
        f32x4 L6 = ntload_f4(logit4 + 7 * (size_t)t + 6);

        i32x4 lab = ntload_i4(label4 + t);

        i32x4 r0 = ntload_i4(repr4 + 3 * (size_t)t + 0);
        i32x4 r1 = ntload_i4(repr4 + 3 * (size_t)t + 1);
        i32x4 r2 = ntload_i4(repr4 + 3 * (size_t)t + 2);

        unsigned m0 = (1u << r0[0]) | (1u << r0[1]) | (1u << r0[2]);
        unsigned m1 = (1u << r0[3]) | (1u << r1[0]) | (1u << r1[1]);
        unsigned m2 = (1u << r1[2]) | (1u << r1[3]) | (1u << r2[0]);
        unsigned m3 = (1u << r2[1]) | (1u << r2[2]) | (1u << r2[3]);

        float tgt[4];
        tgt[0] = (lab[0] == 1) ? 1.0f : 0.0f;
        tgt[1] = (lab[1] == 1) ? 1.0f : 0.0f;
        tgt[2] = (lab[2] == 1) ? 1.0f : 0.0f;
        tgt[3] = (lab[3] == 1) ? 1.0f : 0.0f;
        unsigned mk[4] = {m0, m1, m2, m3};

        float f[28];
        f[0]=L0[0];  f[1]=L0[1];  f[2]=L0[2];  f[3]=L0[3];
        f[4]=L1[0];  f[5]=L1[1];  f[6]=L1[2];  f[7]=L1[3];
        f[8]=L2[0];  f[9]=L2[1];  f[10]=L2[2]; f[11]=L2[3];
        f[12]=L3[0]; f[13]=L3[1]; f[14]=L3[2]; f[15]=L3[3];
        f[16]=L4[0]; f[17]=L4[1]; f[18]=L4[2]; f[19]=L4[3];
        f[20]=L5[0]; f[21]=L5[1]; f[22]=L5[2]; f[23]=L5[3];
        f[24]=L6[0]; f[25]=L6[1]; f[26]=L6[2]; f[27]=L6[3];

        #pragma unroll
        for (int k = 0; k < 4; ++k) {
            #pragma unroll
            for (int j = 0; j < NCLS; ++j) {
                float d = f[7 * k + j] - tgt[k];
                acc += ((mk[k] >> j) & 1u) ? fabsf(d) : fmaxf(d, 0.0f);
            }
        }
    }

    // wave (64-lane) butterfly reduce
    #pragma unroll
    for (int off = 32; off > 0; off >>= 1)
        acc += __shfl_down(acc, off, 64);

    __shared__ float wave_sums[4];
    int lane = threadIdx.x & 63;
    int wid  = threadIdx.x >> 6;
    if (lane == 0) wave_sums[wid] = acc;
    __syncthreads();

    // one contention-free store per block (ws slot), no atomics
    if (threadIdx.x == 0)
        partials[blockIdx.x] = wave_sums[0] + wave_sums[1] + wave_sums[2] + wave_sums[3];
}

__global__ __launch_bounds__(256) void reduce_partials_kernel(
    const float* __restrict__ partials, int nblk,
    const float* __restrict__ logit, const int* __restrict__ label,
    const int* __restrict__ repr, int tail_start, int B,
    float* __restrict__ out)
{
    float a = 0.0f;
    for (int i = threadIdx.x; i < nblk; i += 256)
        a += partials[i];

    // rows beyond 4*nchunk (B % 4; zero for B=4M)
    for (int i = tail_start + threadIdx.x; i < B; i += 256) {
        float tgt = (label[i] == 1) ? 1.0f : 0.0f;
        unsigned m = (1u << repr[3*i]) | (1u << repr[3*i+1]) | (1u << repr[3*i+2]);
        #pragma unroll
        for (int j = 0; j < NCLS; ++j) {
            float d = logit[i * NCLS + j] - tgt;
            a += ((m >> j) & 1u) ? fabsf(d) : fmaxf(d, 0.0f);
        }
    }

    #pragma unroll
    for (int off = 32; off > 0; off >>= 1)
        a += __shfl_down(a, off, 64);

    __shared__ float wave_sums[4];
    if ((threadIdx.x & 63) == 0) wave_sums[threadIdx.x >> 6] = a;
    __syncthreads();
    if (threadIdx.x == 0)
        out[0] = wave_sums[0] + wave_sums[1] + wave_sums[2] + wave_sums[3];
}

extern "C" void kernel_launch(void* const* d_in, const int* in_sizes, int n_in,
                              void* d_out, int out_size, void* d_ws, size_t ws_size,
                              hipStream_t stream) {
    const f32x4* logit4 = (const f32x4*)d_in[0];
    const i32x4* label4 = (const i32x4*)d_in[1];
    const i32x4* repr4  = (const i32x4*)d_in[2];
    float*       out    = (float*)d_out;
    float*       partials = (float*)d_ws;

    int B = in_sizes[1];        // label is [B]
    int nchunk = B / 4;         // 1,000,000
    int tail_start = nchunk * 4;

    hinge_partial_kernel<<<NBLK, 256, 0, stream>>>(logit4, label4, repr4, partials, nchunk);
    reduce_partials_kernel<<<1, 256, 0, stream>>>(
        partials, NBLK, (const float*)d_in[0], (const int*)d_in[1],
        (const int*)d_in[2], tail_start, B, out);
}